// Round 1
// baseline (155.180 us; speedup 1.0000x reference)
//
#include <hip/hip_runtime.h>
#include <math.h>

#define HH 1024
#define WW 1024
#define KK 31
#define PADK 15
#define RB 64
#define TPB 256
#define NB_PER_IMG (HH / RB)   // 16 bands per image
#define EPSV 1e-5f
#define INV_K2 (1.0f / 961.0f)

__device__ __forceinline__ float lcn_px(float xv, float hs, float hq) {
    float mean = hs * INV_K2;
    float sq   = hq * INV_K2;
    float var  = sq - mean * mean;
    float sd   = sqrtf(fmaxf(var, EPSV));
    float nrm  = (xv - mean) / (sd + EPSV);
    float enh  = 1.0f / (1.0f + __expf(-0.5f * nrm));
    return xv * (1.0f - 0.8f) + enh * 0.8f;
}

__global__ __launch_bounds__(TPB) void lcn_kernel(const float* __restrict__ x,
                                                  float* __restrict__ out) {
    // vertical-sum rows staged in LDS with 16-elem zero halos on both sides
    // lsx[i] corresponds to column (i - 16); valid cols 0..1023 -> idx 16..1039
    __shared__ __align__(16) float lsx[1056];
    __shared__ __align__(16) float lsq[1056];

    const int blk  = blockIdx.x;
    const int b    = blk / NB_PER_IMG;
    const int band = blk % NB_PER_IMG;
    const int r0   = band * RB;
    const int t    = threadIdx.x;
    const int c0   = t * 4;            // this thread owns columns c0..c0+3

    const float* __restrict__ img  = x   + (size_t)b * HH * WW;
    float* __restrict__       oimg = out + (size_t)b * HH * WW;

    if (t < 16) {
        lsx[t] = 0.f;        lsq[t] = 0.f;
        lsx[1040 + t] = 0.f; lsq[1040 + t] = 0.f;
    }

    // --- init vertical sliding sums for output row r0 (rows r0-15 .. r0+15, clipped) ---
    float4 s  = make_float4(0.f, 0.f, 0.f, 0.f);
    float4 s2 = make_float4(0.f, 0.f, 0.f, 0.f);
    {
        int lo = r0 - PADK; if (lo < 0) lo = 0;
        int hi = r0 + PADK; if (hi > HH - 1) hi = HH - 1;
        for (int r = lo; r <= hi; ++r) {
            float4 v = *reinterpret_cast<const float4*>(img + (size_t)r * WW + c0);
            s.x  += v.x;       s.y  += v.y;       s.z  += v.z;       s.w  += v.w;
            s2.x += v.x * v.x; s2.y += v.y * v.y; s2.z += v.z * v.z; s2.w += v.w * v.w;
        }
    }
    *reinterpret_cast<float4*>(lsx + 16 + c0) = s;
    *reinterpret_cast<float4*>(lsq + 16 + c0) = s2;

    for (int orow = r0; orow < r0 + RB; ++orow) {
        if (orow > r0) {
            const int radd = orow + PADK;
            const int rsub = orow - PADK - 1;
            if (radd < HH) {
                float4 v = *reinterpret_cast<const float4*>(img + (size_t)radd * WW + c0);
                s.x  += v.x;       s.y  += v.y;       s.z  += v.z;       s.w  += v.w;
                s2.x += v.x * v.x; s2.y += v.y * v.y; s2.z += v.z * v.z; s2.w += v.w * v.w;
            }
            if (rsub >= 0) {
                float4 v = *reinterpret_cast<const float4*>(img + (size_t)rsub * WW + c0);
                s.x  -= v.x;       s.y  -= v.y;       s.z  -= v.z;       s.w  -= v.w;
                s2.x -= v.x * v.x; s2.y -= v.y * v.y; s2.z -= v.z * v.z; s2.w -= v.w * v.w;
            }
            __syncthreads();   // prior horizontal reads done before we overwrite
            *reinterpret_cast<float4*>(lsx + 16 + c0) = s;
            *reinterpret_cast<float4*>(lsq + 16 + c0) = s2;
        }
        __syncthreads();       // vertical sums visible to all

        // --- horizontal 31-window sums for 4 columns (c0 .. c0+3) ---
        // output col c needs lsx idx (c+1 .. c+31); across q=0..3 -> idx c0+1 .. c0+34
        float wx[36], wq[36];
        #pragma unroll
        for (int q = 0; q < 9; ++q) {
            float4 a = *reinterpret_cast<const float4*>(lsx + c0 + 4 * q);
            wx[4*q+0] = a.x; wx[4*q+1] = a.y; wx[4*q+2] = a.z; wx[4*q+3] = a.w;
            float4 c = *reinterpret_cast<const float4*>(lsq + c0 + 4 * q);
            wq[4*q+0] = c.x; wq[4*q+1] = c.y; wq[4*q+2] = c.z; wq[4*q+3] = c.w;
        }

        // base = sum of idx 4..31 (28 elems, common to all 4 windows); 4 accumulators
        float a0 = 0.f, a1 = 0.f, a2 = 0.f, a3 = 0.f;
        float b0 = 0.f, b1 = 0.f, b2 = 0.f, b3 = 0.f;
        #pragma unroll
        for (int j = 4; j < 32; j += 4) {
            a0 += wx[j];   a1 += wx[j+1]; a2 += wx[j+2]; a3 += wx[j+3];
            b0 += wq[j];   b1 += wq[j+1]; b2 += wq[j+2]; b3 += wq[j+3];
        }
        float base  = (a0 + a1) + (a2 + a3);
        float base2 = (b0 + b1) + (b2 + b3);

        float hs0 = base  + wx[1]  + wx[2]  + wx[3];
        float hs1 = base  + wx[2]  + wx[3]  + wx[32];
        float hs2 = base  + wx[3]  + wx[32] + wx[33];
        float hs3 = base  + wx[32] + wx[33] + wx[34];
        float hq0 = base2 + wq[1]  + wq[2]  + wq[3];
        float hq1 = base2 + wq[2]  + wq[3]  + wq[32];
        float hq2 = base2 + wq[3]  + wq[32] + wq[33];
        float hq3 = base2 + wq[32] + wq[33] + wq[34];

        float4 xc = *reinterpret_cast<const float4*>(img + (size_t)orow * WW + c0);

        float4 ro;
        ro.x = lcn_px(xc.x, hs0, hq0);
        ro.y = lcn_px(xc.y, hs1, hq1);
        ro.z = lcn_px(xc.z, hs2, hq2);
        ro.w = lcn_px(xc.w, hs3, hq3);
        *reinterpret_cast<float4*>(oimg + (size_t)orow * WW + c0) = ro;
    }
}

extern "C" void kernel_launch(void* const* d_in, const int* in_sizes, int n_in,
                              void* d_out, int out_size, void* d_ws, size_t ws_size,
                              hipStream_t stream) {
    const float* xin = (const float*)d_in[0];
    float* out = (float*)d_out;
    const int B = in_sizes[0] / (HH * WW);   // 32
    dim3 grid(B * NB_PER_IMG);
    dim3 block(TPB);
    hipLaunchKernelGGL(lcn_kernel, grid, block, 0, stream, xin, out);
}

// Round 2
// 113.873 us; speedup vs baseline: 1.3627x; 1.3627x over previous
//
#include <hip/hip_runtime.h>
#include <math.h>

#define HH 1024
#define WW 1024
#define PADK 15
#define RB 32
#define TPB 256
#define NB_PER_IMG (HH / RB)   // 32 bands per image
#define EPSV 1e-5f
#define INV_K2 (1.0f / 961.0f)

__device__ __forceinline__ float lcn_px(float xv, float hs, float hq) {
    float mean = hs * INV_K2;
    float sq   = hq * INV_K2;
    float var  = sq - mean * mean;
    float sd   = sqrtf(fmaxf(var, EPSV));
    float nrm  = (xv - mean) * __builtin_amdgcn_rcpf(sd + EPSV);
    float enh  = 1.0f / (1.0f + __expf(-0.5f * nrm));
    return xv * 0.2f + enh * 0.8f;
}

__global__ __launch_bounds__(TPB) void lcn_kernel(const float* __restrict__ x,
                                                  float* __restrict__ out) {
    // Per-wave private LDS regions: 288 sums (16 halo | 256 owned | 16 halo),
    // padded to 296 floats. No __syncthreads anywhere: all LDS traffic is
    // wave-local and DS ops are in-order within a wave.
    __shared__ __align__(16) float sxl[4][296];
    __shared__ __align__(16) float sql[4][296];

    const int blk  = blockIdx.x;
    const int b    = blk / NB_PER_IMG;
    const int band = blk % NB_PER_IMG;
    const int r0   = band * RB;
    const int t    = threadIdx.x;
    const int w    = t >> 6;          // wave id 0..3
    const int l    = t & 63;          // lane
    const int wc0  = w * 256;         // wave's first owned column
    const int c0   = wc0 + l * 4;     // this lane's owned columns c0..c0+3

    float* __restrict__ sxw = sxl[w];
    float* __restrict__ sqw = sql[w];

    // halo assignment: lanes 0..3 -> left halo float4s, lanes 4..7 -> right
    int hcol = 0;
    bool hlane = (l < 8);
    if (l < 4)      hcol = wc0 - 16 + 4 * l;
    else if (l < 8) hcol = wc0 + 256 + 4 * (l - 4);
    const bool hvalid = hlane && (hcol >= 0) && (hcol < WW);
    const int  hidx   = (l < 4) ? 4 * l : 272 + 4 * (l - 4);

    const float* __restrict__ img  = x   + (size_t)b * HH * WW;
    float* __restrict__       oimg = out + (size_t)b * HH * WW;

    float4 s   = make_float4(0.f, 0.f, 0.f, 0.f);
    float4 s2  = make_float4(0.f, 0.f, 0.f, 0.f);
    float4 hs  = make_float4(0.f, 0.f, 0.f, 0.f);
    float4 hs2 = make_float4(0.f, 0.f, 0.f, 0.f);

    // --- init vertical sliding sums for output row r0 ---
    {
        int lo = r0 - PADK; if (lo < 0) lo = 0;
        int hi = r0 + PADK;                    // r0 <= 992 -> hi <= 1007 < HH
        for (int r = lo; r <= hi; ++r) {
            const float* rowp = img + (size_t)r * WW;
            float4 v = *reinterpret_cast<const float4*>(rowp + c0);
            s.x  += v.x;       s.y  += v.y;       s.z  += v.z;       s.w  += v.w;
            s2.x += v.x * v.x; s2.y += v.y * v.y; s2.z += v.z * v.z; s2.w += v.w * v.w;
            if (hvalid) {
                float4 hv = *reinterpret_cast<const float4*>(rowp + hcol);
                hs.x  += hv.x;        hs.y  += hv.y;        hs.z  += hv.z;        hs.w  += hv.w;
                hs2.x += hv.x * hv.x; hs2.y += hv.y * hv.y; hs2.z += hv.z * hv.z; hs2.w += hv.w * hv.w;
            }
        }
    }

    for (int orow = r0; orow < r0 + RB; ++orow) {
        if (orow > r0) {
            const int radd = orow + PADK;
            const int rsub = orow - PADK - 1;
            if (radd < HH) {
                const float* rowp = img + (size_t)radd * WW;
                float4 v = *reinterpret_cast<const float4*>(rowp + c0);
                s.x  += v.x;       s.y  += v.y;       s.z  += v.z;       s.w  += v.w;
                s2.x += v.x * v.x; s2.y += v.y * v.y; s2.z += v.z * v.z; s2.w += v.w * v.w;
                if (hvalid) {
                    float4 hv = *reinterpret_cast<const float4*>(rowp + hcol);
                    hs.x  += hv.x;        hs.y  += hv.y;        hs.z  += hv.z;        hs.w  += hv.w;
                    hs2.x += hv.x * hv.x; hs2.y += hv.y * hv.y; hs2.z += hv.z * hv.z; hs2.w += hv.w * hv.w;
                }
            }
            if (rsub >= 0) {
                const float* rowp = img + (size_t)rsub * WW;
                float4 v = *reinterpret_cast<const float4*>(rowp + c0);
                s.x  -= v.x;       s.y  -= v.y;       s.z  -= v.z;       s.w  -= v.w;
                s2.x -= v.x * v.x; s2.y -= v.y * v.y; s2.z -= v.z * v.z; s2.w -= v.w * v.w;
                if (hvalid) {
                    float4 hv = *reinterpret_cast<const float4*>(rowp + hcol);
                    hs.x  -= hv.x;        hs.y  -= hv.y;        hs.z  -= hv.z;        hs.w  -= hv.w;
                    hs2.x -= hv.x * hv.x; hs2.y -= hv.y * hv.y; hs2.z -= hv.z * hv.z; hs2.w -= hv.w * hv.w;
                }
            }
        }

        // write this wave's vertical sums (owned + halo) to its LDS region
        *reinterpret_cast<float4*>(sxw + 16 + 4 * l) = s;
        *reinterpret_cast<float4*>(sqw + 16 + 4 * l) = s2;
        if (hlane) {
            *reinterpret_cast<float4*>(sxw + hidx) = hs;   // zeros when !hvalid
            *reinterpret_cast<float4*>(sqw + hidx) = hs2;
        }
        // no barrier: DS ops are in-order within a wave

        // --- horizontal 31-window sums for 4 columns ---
        // window for owned col (16+4l+q) needs idx (4l+q+1 .. 4l+q+31)
        float wx[36], wq[36];
        #pragma unroll
        for (int m = 0; m < 9; ++m) {
            float4 a = *reinterpret_cast<const float4*>(sxw + 4 * l + 4 * m);
            wx[4*m+0] = a.x; wx[4*m+1] = a.y; wx[4*m+2] = a.z; wx[4*m+3] = a.w;
            float4 c = *reinterpret_cast<const float4*>(sqw + 4 * l + 4 * m);
            wq[4*m+0] = c.x; wq[4*m+1] = c.y; wq[4*m+2] = c.z; wq[4*m+3] = c.w;
        }

        float a0 = 0.f, a1 = 0.f, a2 = 0.f, a3 = 0.f;
        float b0 = 0.f, b1 = 0.f, b2 = 0.f, b3 = 0.f;
        #pragma unroll
        for (int j = 4; j < 32; j += 4) {
            a0 += wx[j];   a1 += wx[j+1]; a2 += wx[j+2]; a3 += wx[j+3];
            b0 += wq[j];   b1 += wq[j+1]; b2 += wq[j+2]; b3 += wq[j+3];
        }
        float base  = (a0 + a1) + (a2 + a3);
        float base2 = (b0 + b1) + (b2 + b3);

        float hs0 = base  + wx[1]  + wx[2]  + wx[3];
        float hs1 = base  + wx[2]  + wx[3]  + wx[32];
        float hs2_ = base + wx[3]  + wx[32] + wx[33];
        float hs3 = base  + wx[32] + wx[33] + wx[34];
        float hq0 = base2 + wq[1]  + wq[2]  + wq[3];
        float hq1 = base2 + wq[2]  + wq[3]  + wq[32];
        float hq2 = base2 + wq[3]  + wq[32] + wq[33];
        float hq3 = base2 + wq[32] + wq[33] + wq[34];

        float4 xc = *reinterpret_cast<const float4*>(img + (size_t)orow * WW + c0);

        float4 ro;
        ro.x = lcn_px(xc.x, hs0, hq0);
        ro.y = lcn_px(xc.y, hs1, hq1);
        ro.z = lcn_px(xc.z, hs2_, hq2);
        ro.w = lcn_px(xc.w, hs3, hq3);
        *reinterpret_cast<float4*>(oimg + (size_t)orow * WW + c0) = ro;
    }
}

extern "C" void kernel_launch(void* const* d_in, const int* in_sizes, int n_in,
                              void* d_out, int out_size, void* d_ws, size_t ws_size,
                              hipStream_t stream) {
    const float* xin = (const float*)d_in[0];
    float* out = (float*)d_out;
    const int B = in_sizes[0] / (HH * WW);   // 32
    dim3 grid(B * NB_PER_IMG);
    dim3 block(TPB);
    hipLaunchKernelGGL(lcn_kernel, grid, block, 0, stream, xin, out);
}